// Round 1
// baseline (3459.015 us; speedup 1.0000x reference)
//
#include <hip/hip_runtime.h>
#include <math.h>

// ---------------------------------------------------------------------------
// Problem constants: B=2, S=4096, D=256, IN=3D=768, N_BASIS=8, grid h=0.4
// softmax(scores + rowconst) == softmax(scores) -> q@view_emb bias dropped.
// ---------------------------------------------------------------------------

__device__ __forceinline__ float wave_sum(float v) {
#pragma unroll
  for (int o = 32; o > 0; o >>= 1) v += __shfl_down(v, o, 64);
  return v;
}
__device__ __forceinline__ float wave_max(float v) {
#pragma unroll
  for (int o = 32; o > 0; o >>= 1) v = fmaxf(v, __shfl_down(v, o, 64));
  return v;
}

// ---------------------------------------------------------------------------
// Tiled fp32 GEMM: C[M,N] = scale * (A @ opB) + bias
//   TRANSB=true :  opB = B^T with B stored [N,K] row-major (QKV, Q@K^T)
//   TRANSB=false:  opB = B   with B stored [K,N] row-major (P@V)
// BM=BN=64, BK=16, 256 threads, 4x4 microtile. M,N % 64 == 0, K % 16 == 0.
// ---------------------------------------------------------------------------
template <bool TRANSB>
__global__ __launch_bounds__(256) void gemm_tile(
    const float* __restrict__ A, const float* __restrict__ B,
    const float* __restrict__ bias, float* __restrict__ C,
    int M, int N, int K, float scale) {
  __shared__ float As[16][68];
  __shared__ float Bs[16][68];
  const int tid = threadIdx.x;
  const int tx = tid & 15;       // col group (4 cols)
  const int ty = tid >> 4;       // row group (4 rows)
  const int m0 = blockIdx.y << 6;
  const int n0 = blockIdx.x << 6;
  const int lr = tid >> 2;         // 0..63  (A / B^T tile row)
  const int lc = (tid & 3) << 2;   // 0,4,8,12 (k offset)
  const int bkr = tid >> 4;        // 0..15 (B NN tile k-row)
  const int bc = (tid & 15) << 2;  // 0..60 (B NN tile col)

  float acc[4][4] = {};

  for (int k0 = 0; k0 < K; k0 += 16) {
    float4 av = *(const float4*)(A + (size_t)(m0 + lr) * K + k0 + lc);
    float4 bv;
    if constexpr (TRANSB) {
      bv = *(const float4*)(B + (size_t)(n0 + lr) * K + k0 + lc);
    } else {
      bv = *(const float4*)(B + (size_t)(k0 + bkr) * N + n0 + bc);
    }
    __syncthreads();  // previous tile fully consumed
    As[lc + 0][lr] = av.x;
    As[lc + 1][lr] = av.y;
    As[lc + 2][lr] = av.z;
    As[lc + 3][lr] = av.w;
    if constexpr (TRANSB) {
      Bs[lc + 0][lr] = bv.x;
      Bs[lc + 1][lr] = bv.y;
      Bs[lc + 2][lr] = bv.z;
      Bs[lc + 3][lr] = bv.w;
    } else {
      *(float4*)&Bs[bkr][bc] = bv;
    }
    __syncthreads();
#pragma unroll
    for (int kk = 0; kk < 16; ++kk) {
      float a[4], b[4];
      *(float4*)&a[0] = *(const float4*)&As[kk][ty << 2];
      *(float4*)&b[0] = *(const float4*)&Bs[kk][tx << 2];
#pragma unroll
      for (int i = 0; i < 4; ++i)
#pragma unroll
        for (int j = 0; j < 4; ++j) acc[i][j] = fmaf(a[i], b[j], acc[i][j]);
    }
  }

  float bb[4] = {0.f, 0.f, 0.f, 0.f};
  if (bias) *(float4*)&bb[0] = *(const float4*)(bias + n0 + (tx << 2));
#pragma unroll
  for (int i = 0; i < 4; ++i) {
    alignas(16) float r[4];
#pragma unroll
    for (int j = 0; j < 4; ++j) r[j] = fmaf(acc[i][j], scale, bb[j]);
    *(float4*)(C + (size_t)(m0 + (ty << 2) + i) * N + n0 + (tx << 2)) =
        *(float4*)&r[0];
  }
}

// ---------------------------------------------------------------------------
// In-place row softmax over 4096 columns. One block (256 thr) per row.
// ---------------------------------------------------------------------------
__global__ __launch_bounds__(256) void softmax_kernel(float* __restrict__ sc) {
  __shared__ float red[4];
  const int tid = threadIdx.x;
  float* p = sc + (size_t)blockIdx.x * 4096;
  float v[16];
  float mx = -1e30f;
#pragma unroll
  for (int t = 0; t < 16; ++t) {
    v[t] = p[tid + (t << 8)];
    mx = fmaxf(mx, v[t]);
  }
  mx = wave_max(mx);
  if ((tid & 63) == 0) red[tid >> 6] = mx;
  __syncthreads();
  mx = fmaxf(fmaxf(red[0], red[1]), fmaxf(red[2], red[3]));
  __syncthreads();
  float s = 0.f;
#pragma unroll
  for (int t = 0; t < 16; ++t) {
    v[t] = __expf(v[t] - mx);
    s += v[t];
  }
  s = wave_sum(s);
  if ((tid & 63) == 0) red[tid >> 6] = s;
  __syncthreads();
  s = red[0] + red[1] + red[2] + red[3];
  const float inv = 1.0f / s;
#pragma unroll
  for (int t = 0; t < 16; ++t) p[tid + (t << 8)] = v[t] * inv;
}

// ---------------------------------------------------------------------------
// residual + LayerNorm, writes into concat buffer x[n, vIdx*256 + d]
// one block per row n (B*S rows), 256 threads = D
// ---------------------------------------------------------------------------
__global__ __launch_bounds__(256) void resid_ln_kernel(
    const float* __restrict__ att, const float* __restrict__ tok,
    const float* __restrict__ gamma, const float* __restrict__ beta,
    float* __restrict__ x, int vIdx) {
  __shared__ float red[4];
  const int n = blockIdx.x;
  const int d = threadIdx.x;
  const float y = att[(size_t)n * 256 + d] + tok[(size_t)n * 256 + d];
  float s = wave_sum(y);
  if ((d & 63) == 0) red[d >> 6] = s;
  __syncthreads();
  const float mu = (red[0] + red[1] + red[2] + red[3]) * (1.0f / 256.0f);
  __syncthreads();
  const float c = y - mu;
  float s2 = wave_sum(c * c);
  if ((d & 63) == 0) red[d >> 6] = s2;
  __syncthreads();
  const float var = (red[0] + red[1] + red[2] + red[3]) * (1.0f / 256.0f);
  const float rs = rsqrtf(var + 1e-5f);
  x[(size_t)n * 768 + vIdx * 256 + d] = c * rs * gamma[d] + beta[d];
}

// ---------------------------------------------------------------------------
// prep: bwT[i][o] = base_weight[o][i];  swsT2[(i*256+o)*8+f] = sw[o][i][f]*scaler[o][i]
// ---------------------------------------------------------------------------
__global__ __launch_bounds__(256) void prep_kernel(
    const float* __restrict__ bw, const float* __restrict__ sw,
    const float* __restrict__ scaler, float* __restrict__ bwT,
    float* __restrict__ swsT2) {
  const int idx = blockIdx.x * 256 + threadIdx.x;
  const int o = idx & 255;
  const int i = idx >> 8;
  if (i >= 768) return;
  const float s = scaler[(size_t)o * 768 + i];
  bwT[(size_t)i * 256 + o] = bw[(size_t)o * 768 + i];
#pragma unroll
  for (int f = 0; f < 8; ++f)
    swsT2[(((size_t)i * 256 + o) << 3) + f] =
        sw[(((size_t)o * 768 + i) << 3) + f] * s;
}

// ---------------------------------------------------------------------------
// fused KAN: out[n,o] = sum_i silu(x[n,i])*bwT[i,o] + sum_{i,f} B3(x[n,i],f)*sws[i,o,f]
// block tile: 16 rows x 256 cols; chunks of 64 features staged in LDS
// thread: 2 rows x 8 cols (cols strided by 32 for coalescing)
// ---------------------------------------------------------------------------
__global__ __launch_bounds__(256) void kan_kernel(
    const float* __restrict__ x, const float* __restrict__ bwT,
    const float* __restrict__ swsT2, float* __restrict__ out) {
  __shared__ float silu_s[16][64];
  __shared__ float4 bases_s[16][64][2];
  const int tid = threadIdx.x;
  const int row0 = blockIdx.x << 4;
  const int cl = tid & 31;         // col base; cols = cl + j*32
  const int rg = (tid >> 5) << 1;  // rows rg, rg+1

  float acc0[8] = {};
  float acc1[8] = {};

  for (int ch = 0; ch < 12; ++ch) {
    const int i0 = ch << 6;
    __syncthreads();  // previous chunk consumed
#pragma unroll
    for (int t = 0; t < 4; ++t) {
      const int e = tid + (t << 8);
      const int r = e >> 6, c = e & 63;
      const float xv = x[(size_t)(row0 + r) * 768 + i0 + c];
      silu_s[r][c] = xv / (1.0f + __expf(-xv));
      // Cox-de Boor, uniform knots g[m] = 0.4*(m-3) - 1, m = 0..11
      float b[11];
#pragma unroll
      for (int m = 0; m < 11; ++m) {
        const float g0 = 0.4f * (float)(m - 3) - 1.0f;
        const float g1 = 0.4f * (float)(m - 2) - 1.0f;
        b[m] = (xv >= g0 && xv < g1) ? 1.0f : 0.0f;
      }
#pragma unroll
      for (int k = 1; k <= 3; ++k) {
        const float inv = 1.0f / (0.4f * (float)k);
#pragma unroll
        for (int m = 0; m + k < 11; ++m) {
          const float gm = 0.4f * (float)(m - 3) - 1.0f;
          const float gmk1 = 0.4f * (float)(m + k - 2) - 1.0f;  // g[m+k+1]
          b[m] = (xv - gm) * inv * b[m] + (gmk1 - xv) * inv * b[m + 1];
        }
      }
      bases_s[r][c][0] = make_float4(b[0], b[1], b[2], b[3]);
      bases_s[r][c][1] = make_float4(b[4], b[5], b[6], b[7]);
    }
    __syncthreads();

    for (int i = 0; i < 64; ++i) {
      const int ig = i0 + i;
      const float sv0 = silu_s[rg][i];
      const float sv1 = silu_s[rg + 1][i];
      const float4 p00 = bases_s[rg][i][0], p01 = bases_s[rg][i][1];
      const float4 p10 = bases_s[rg + 1][i][0], p11 = bases_s[rg + 1][i][1];
      const float* bwp = bwT + (size_t)ig * 256 + cl;
      const float4* wp = (const float4*)(swsT2 + ((size_t)ig * 256 + cl) * 8);
#pragma unroll
      for (int j = 0; j < 8; ++j) {
        const float wb = bwp[j * 32];
        const float4 w0 = wp[j * 64];
        const float4 w1 = wp[j * 64 + 1];
        acc0[j] += sv0 * wb + p00.x * w0.x + p00.y * w0.y + p00.z * w0.z +
                   p00.w * w0.w + p01.x * w1.x + p01.y * w1.y + p01.z * w1.z +
                   p01.w * w1.w;
        acc1[j] += sv1 * wb + p10.x * w0.x + p10.y * w0.y + p10.z * w0.z +
                   p10.w * w0.w + p11.x * w1.x + p11.y * w1.y + p11.z * w1.z +
                   p11.w * w1.w;
      }
    }
  }

  const int r0 = row0 + rg;
#pragma unroll
  for (int j = 0; j < 8; ++j) {
    out[(size_t)r0 * 256 + cl + j * 32] = acc0[j];
    out[(size_t)(r0 + 1) * 256 + cl + j * 32] = acc1[j];
  }
}

// ---------------------------------------------------------------------------
extern "C" void kernel_launch(void* const* d_in, const int* in_sizes, int n_in,
                              void* d_out, int out_size, void* d_ws,
                              size_t ws_size, hipStream_t stream) {
  const int B = 2, S = 4096, D = 256;
  const size_t SD = (size_t)S * D;       // per-batch matrix
  const size_t BSD = (size_t)B * SD;     // 2,097,152 floats

  const float* tok[3] = {(const float*)d_in[0], (const float*)d_in[1],
                         (const float*)d_in[2]};
  const float* wq = (const float*)d_in[3];
  const float* bq = (const float*)d_in[4];
  const float* wk = (const float*)d_in[5];
  const float* bk = (const float*)d_in[6];
  const float* wv = (const float*)d_in[7];
  const float* bv = (const float*)d_in[8];
  // d_in[9] = view_emb: contributes a per-row constant to pre-softmax scores,
  // which softmax cancels exactly -> unused.
  const float* lng[3] = {(const float*)d_in[10], (const float*)d_in[12],
                         (const float*)d_in[14]};
  const float* lnb[3] = {(const float*)d_in[11], (const float*)d_in[13],
                         (const float*)d_in[15]};
  const float* bw = (const float*)d_in[16];
  const float* sw = (const float*)d_in[17];
  const float* scaler = (const float*)d_in[18];

  float* ws = (float*)d_ws;
  float* q = ws;                         // [B*S, D] ; later reused as att out
  float* kbuf = q + BSD;                 // [B*S, D]
  float* vbuf = kbuf + BSD;              // [B*S, D]
  float* sc = vbuf + BSD;                // [S, S] reused per (view,batch)
  float* x = sc + (size_t)S * S;         // [B*S, 768] concat of LN outputs
  float* swsT2 = x + (size_t)B * S * 768;       // [768,256,8]
  float* bwT = swsT2 + (size_t)768 * 256 * 8;   // [768,256]
  // total ws use: ~124.5 MB

  prep_kernel<<<768, 256, 0, stream>>>(bw, sw, scaler, bwT, swsT2);

  const dim3 gq(D / 64, (B * S) / 64);
  for (int v = 0; v < 3; ++v) {
    gemm_tile<true><<<gq, 256, 0, stream>>>(tok[v], wq, bq, q, B * S, D, D, 1.0f);
    gemm_tile<true><<<gq, 256, 0, stream>>>(tok[v], wk, bk, kbuf, B * S, D, D, 1.0f);
    gemm_tile<true><<<gq, 256, 0, stream>>>(tok[v], wv, bv, vbuf, B * S, D, D, 1.0f);
    for (int b = 0; b < B; ++b) {
      gemm_tile<true><<<dim3(S / 64, S / 64), 256, 0, stream>>>(
          q + b * SD, kbuf + b * SD, nullptr, sc, S, S, D, 0.0625f);
      softmax_kernel<<<S, 256, 0, stream>>>(sc);
      // att overwrites q for this batch (q no longer needed after scores)
      gemm_tile<false><<<dim3(D / 64, S / 64), 256, 0, stream>>>(
          sc, vbuf + b * SD, nullptr, q + b * SD, S, D, S, 1.0f);
    }
    resid_ln_kernel<<<B * S, 256, 0, stream>>>(q, tok[v], lng[v], lnb[v], x, v);
  }

  kan_kernel<<<(B * S) / 16, 256, 0, stream>>>(x, bwT, swsT2, (float*)d_out);
}

// Round 2
// 875.088 us; speedup vs baseline: 3.9528x; 3.9528x over previous
//
#include <hip/hip_runtime.h>
#include <hip/hip_bf16.h>
#include <math.h>

// ---------------------------------------------------------------------------
// B=2, S=4096, D=256, IN=768, N_BASIS=8, spline grid h=0.4
// softmax(scores + row-const) == softmax(scores) -> q@view_emb bias dropped.
// All GEMMs via one bf16 MFMA kernel (C = scale*(A @ B^T) + bias):
//   QKV   : tokb[8192,256]  @ wqkvb[768,256]^T   -> qkv bf16 (bias)
//   scores: q[4096,256]     @ k[4096,256]^T      -> sc fp32  (scale 1/16)
//   PV    : P[4096,4096]    @ vT[256,4096]^T     -> att fp32 (z=2 batch)
//   KAN   : basis[8192,6912]@ Wmat[256,6912]^T   -> out fp32
// ---------------------------------------------------------------------------

typedef __hip_bfloat16 bf16;
using bf16x8 = __attribute__((ext_vector_type(8))) __bf16;
using f32x4  = __attribute__((ext_vector_type(4))) float;

__device__ __forceinline__ void load_lds16(const void* g, void* l) {
  __builtin_amdgcn_global_load_lds((__attribute__((address_space(1))) void*)g,
                                   (__attribute__((address_space(3))) void*)l,
                                   16, 0, 0);
}

__device__ __forceinline__ float wave_sum(float v) {
#pragma unroll
  for (int o = 32; o > 0; o >>= 1) v += __shfl_down(v, o, 64);
  return v;
}
__device__ __forceinline__ float wave_max(float v) {
#pragma unroll
  for (int o = 32; o > 0; o >>= 1) v = fmaxf(v, __shfl_down(v, o, 64));
  return v;
}

// ---------------------------------------------------------------------------
// bf16 MFMA GEMM, BT form: C[m,n] = scale * sum_k A[m,k]*B[n,k] + bias[n]
// 128x128 block, BK=32, 256 thr = 4 waves (2x2), wave = 4x4 frags of 16x16x32.
// LDS staged via global_load_lds(16B); granules XOR-swizzled so the
// ds_read_b128 fragment reads are <=2-way bank conflicted (free, m136).
// ---------------------------------------------------------------------------
template <typename OutT>
__global__ __launch_bounds__(256) void mfma_gemm_bt(
    const bf16* __restrict__ A, const bf16* __restrict__ B,
    const float* __restrict__ bias, OutT* __restrict__ C, int K, int lda,
    int ldb, int ldc, size_t zsA, size_t zsB, size_t zsC, float scale) {
  __shared__ __align__(16) bf16 As[4096];  // [128 rows][32 k] (swizzled)
  __shared__ __align__(16) bf16 Bs[4096];
  const int tid = (int)threadIdx.x;
  const int lane = tid & 63;
  const int w = tid >> 6;
  const int m0 = (int)blockIdx.y << 7;
  const int n0 = (int)blockIdx.x << 7;
  const size_t z = blockIdx.z;
  A += z * zsA;
  B += z * zsB;
  C += z * zsC;

  // staging: chunk ci = 1024B = 16 rows; lane l -> row ci*16+(l>>2),
  // global granule (l&3)^((l>>3)&3)  (XOR swizzle, see fragment read)
  const int srow = lane >> 2;
  const int qg = (lane & 3) ^ ((lane >> 3) & 3);
  const int ci0 = w, ci1 = w + 4;
  const bf16* gA0 = A + (size_t)(m0 + ci0 * 16 + srow) * lda + qg * 8;
  const bf16* gA1 = A + (size_t)(m0 + ci1 * 16 + srow) * lda + qg * 8;
  const bf16* gB0 = B + (size_t)(n0 + ci0 * 16 + srow) * ldb + qg * 8;
  const bf16* gB1 = B + (size_t)(n0 + ci1 * 16 + srow) * ldb + qg * 8;
  bf16* lA0 = As + ci0 * 512;
  bf16* lA1 = As + ci1 * 512;
  bf16* lB0 = Bs + ci0 * 512;
  bf16* lB1 = Bs + ci1 * 512;

  // fragment read: A[m=lane&15][k=quad*8+j]; granule swizzled by row
  const int m15 = lane & 15, quad = lane >> 4;
  const int fq = quad ^ ((m15 >> 1) & 3);
  const int aoff = m15 * 32 + fq * 8;
  const bf16* pA = As + ((w >> 1) << 11) + aoff;  // + mi*512
  const bf16* pB = Bs + ((w & 1) << 11) + aoff;   // + ni*512

  f32x4 acc[4][4];
#pragma unroll
  for (int mi = 0; mi < 4; ++mi)
#pragma unroll
    for (int ni = 0; ni < 4; ++ni) acc[mi][ni] = (f32x4)(0.0f);

  for (int k0 = 0; k0 < K; k0 += 32) {
    load_lds16(gA0, lA0);
    load_lds16(gA1, lA1);
    load_lds16(gB0, lB0);
    load_lds16(gB1, lB1);
    gA0 += 32; gA1 += 32; gB0 += 32; gB1 += 32;
    __syncthreads();  // drains vmcnt (compiler) -> LDS valid
    bf16x8 av[4], bv[4];
#pragma unroll
    for (int i = 0; i < 4; ++i) {
      av[i] = *(const bf16x8*)(pA + i * 512);
      bv[i] = *(const bf16x8*)(pB + i * 512);
    }
#pragma unroll
    for (int mi = 0; mi < 4; ++mi)
#pragma unroll
      for (int ni = 0; ni < 4; ++ni)
        acc[mi][ni] = __builtin_amdgcn_mfma_f32_16x16x32_bf16(
            av[mi], bv[ni], acc[mi][ni], 0, 0, 0);
    __syncthreads();  // LDS consumed before next stage
  }

  // C/D frag: col = lane&15, row = quad*4 + i  (m89/m91 verified)
  const int crow = m0 + ((w >> 1) << 6) + quad * 4;
  const int ccol = n0 + ((w & 1) << 6) + m15;
#pragma unroll
  for (int ni = 0; ni < 4; ++ni) {
    const int col = ccol + ni * 16;
    const float bb = bias ? bias[col] : 0.0f;
#pragma unroll
    for (int mi = 0; mi < 4; ++mi) {
#pragma unroll
      for (int i = 0; i < 4; ++i) {
        const int row = crow + mi * 16 + i;
        const float v = acc[mi][ni][i] * scale + bb;
        if constexpr (sizeof(OutT) == 2)
          C[(size_t)row * ldc + col] = __float2bfloat16(v);
        else
          C[(size_t)row * ldc + col] = v;
      }
    }
  }
}

// ---------------------------------------------------------------------------
// softmax over 4096 cols, fp32 in (already scaled), bf16 out
// ---------------------------------------------------------------------------
__global__ __launch_bounds__(256) void softmax_kernel(
    const float* __restrict__ sc, bf16* __restrict__ P) {
  __shared__ float red[4];
  const int tid = threadIdx.x;
  const float* p = sc + (size_t)blockIdx.x * 4096;
  bf16* q = P + (size_t)blockIdx.x * 4096;
  float v[16];
  float mx = -1e30f;
#pragma unroll
  for (int t = 0; t < 16; ++t) {
    v[t] = p[tid + (t << 8)];
    mx = fmaxf(mx, v[t]);
  }
  mx = wave_max(mx);
  if ((tid & 63) == 0) red[tid >> 6] = mx;
  __syncthreads();
  mx = fmaxf(fmaxf(red[0], red[1]), fmaxf(red[2], red[3]));
  __syncthreads();
  float s = 0.f;
#pragma unroll
  for (int t = 0; t < 16; ++t) {
    v[t] = __expf(v[t] - mx);
    s += v[t];
  }
  s = wave_sum(s);
  if ((tid & 63) == 0) red[tid >> 6] = s;
  __syncthreads();
  s = red[0] + red[1] + red[2] + red[3];
  const float inv = 1.0f / s;
#pragma unroll
  for (int t = 0; t < 16; ++t) q[tid + (t << 8)] = __float2bfloat16(v[t] * inv);
}

// ---------------------------------------------------------------------------
// residual + LayerNorm -> x[n, vIdx*256 + d] (fp32)
// ---------------------------------------------------------------------------
__global__ __launch_bounds__(256) void resid_ln_kernel(
    const float* __restrict__ att, const float* __restrict__ tok,
    const float* __restrict__ gamma, const float* __restrict__ beta,
    float* __restrict__ x, int vIdx) {
  __shared__ float red[4];
  const int n = blockIdx.x;
  const int d = threadIdx.x;
  const float y = att[(size_t)n * 256 + d] + tok[(size_t)n * 256 + d];
  float s = wave_sum(y);
  if ((d & 63) == 0) red[d >> 6] = s;
  __syncthreads();
  const float mu = (red[0] + red[1] + red[2] + red[3]) * (1.0f / 256.0f);
  __syncthreads();
  const float c = y - mu;
  float s2 = wave_sum(c * c);
  if ((d & 63) == 0) red[d >> 6] = s2;
  __syncthreads();
  const float var = (red[0] + red[1] + red[2] + red[3]) * (1.0f / 256.0f);
  const float rs = rsqrtf(var + 1e-5f);
  x[(size_t)n * 768 + vIdx * 256 + d] = c * rs * gamma[d] + beta[d];
}

// ---------------------------------------------------------------------------
// Wmat[o][i*9+f] = sw[o,i,f]*scaler[o,i] (f<8), Wmat[o][i*9+8] = bw[o,i]
// ---------------------------------------------------------------------------
__global__ __launch_bounds__(256) void prep_w(
    const float* __restrict__ bw, const float* __restrict__ sw,
    const float* __restrict__ scaler, bf16* __restrict__ Wmat) {
  const int o = blockIdx.x;
  for (int ii = 0; ii < 3; ++ii) {
    const int i = ii * 256 + (int)threadIdx.x;
    const float s = scaler[(size_t)o * 768 + i];
    bf16* p = Wmat + (size_t)o * 6912 + i * 9;
    const float* swp = sw + ((size_t)o * 768 + i) * 8;
#pragma unroll
    for (int f = 0; f < 8; ++f) p[f] = __float2bfloat16(swp[f] * s);
    p[8] = __float2bfloat16(bw[(size_t)o * 768 + i]);
  }
}

// wqkvb[768,256] bf16 = concat(wq,wk,wv); bqkv[768] fp32 = concat(bq,bk,bv)
__global__ __launch_bounds__(256) void prep_qkvw(
    const float* __restrict__ wq, const float* __restrict__ wk,
    const float* __restrict__ wv, const float* __restrict__ bq,
    const float* __restrict__ bk, const float* __restrict__ bv,
    bf16* __restrict__ wqkvb, float* __restrict__ bqkv) {
  const int idx = blockIdx.x * 256 + (int)threadIdx.x;
  const int row = idx >> 8, col = idx & 255;
  const float* src = row < 256 ? wq : (row < 512 ? wk : wv);
  wqkvb[idx] = __float2bfloat16(src[((row & 255) << 8) + col]);
  if (idx < 768)
    bqkv[idx] = idx < 256 ? bq[idx] : (idx < 512 ? bk[idx - 256] : bv[idx - 512]);
}

__global__ __launch_bounds__(256) void cast_tok(
    const float4* __restrict__ src, bf16* __restrict__ dst) {
  const int idx = blockIdx.x * 256 + (int)threadIdx.x;
  const float4 v = src[idx];
  bf16* p = dst + (size_t)idx * 4;
  p[0] = __float2bfloat16(v.x);
  p[1] = __float2bfloat16(v.y);
  p[2] = __float2bfloat16(v.z);
  p[3] = __float2bfloat16(v.w);
}

// vT[b][d][s] = qkv[b*4096+s][512+d]
__global__ __launch_bounds__(256) void transpose_v(
    const bf16* __restrict__ qkv, bf16* __restrict__ vT) {
  __shared__ bf16 t[64][65];
  const int s0 = blockIdx.x << 6, d0 = blockIdx.y << 6, b = blockIdx.z;
  const int tid = threadIdx.x;
  const int c = tid & 63, rr = tid >> 6;
  for (int r = 0; r < 64; r += 4)
    t[r + rr][c] = qkv[(size_t)(b * 4096 + s0 + r + rr) * 768 + 512 + d0 + c];
  __syncthreads();
  for (int r = 0; r < 64; r += 4)
    vT[(size_t)(b * 256 + d0 + r + rr) * 4096 + s0 + c] = t[c][r + rr];
}

// ---------------------------------------------------------------------------
// basis[n][i*9+f] = cubic B-spline f of x[n,i] (f<8); f=8 -> silu(x)
// ---------------------------------------------------------------------------
__global__ __launch_bounds__(256) void basis_kernel(
    const float* __restrict__ x, bf16* __restrict__ basis) {
  const int i = blockIdx.x * 256 + (int)threadIdx.x;  // 0..767
  const int n = blockIdx.y;
  const float xv = x[(size_t)n * 768 + i];
  float b[11];
#pragma unroll
  for (int m = 0; m < 11; ++m) {
    const float g0 = 0.4f * (float)(m - 3) - 1.0f;
    const float g1 = 0.4f * (float)(m - 2) - 1.0f;
    b[m] = (xv >= g0 && xv < g1) ? 1.0f : 0.0f;
  }
#pragma unroll
  for (int k = 1; k <= 3; ++k) {
    const float inv = 1.0f / (0.4f * (float)k);
#pragma unroll
    for (int m = 0; m + k < 11; ++m) {
      const float gm = 0.4f * (float)(m - 3) - 1.0f;
      const float gmk1 = 0.4f * (float)(m + k - 2) - 1.0f;
      b[m] = (xv - gm) * inv * b[m] + (gmk1 - xv) * inv * b[m + 1];
    }
  }
  bf16* p = basis + (size_t)n * 6912 + i * 9;
#pragma unroll
  for (int f = 0; f < 8; ++f) p[f] = __float2bfloat16(b[f]);
  p[8] = __float2bfloat16(xv / (1.0f + __expf(-xv)));
}

// ---------------------------------------------------------------------------
extern "C" void kernel_launch(void* const* d_in, const int* in_sizes, int n_in,
                              void* d_out, int out_size, void* d_ws,
                              size_t ws_size, hipStream_t stream) {
  const int S = 4096, D = 256;
  const float* tok[3] = {(const float*)d_in[0], (const float*)d_in[1],
                         (const float*)d_in[2]};
  const float* wq = (const float*)d_in[3];
  const float* bq = (const float*)d_in[4];
  const float* wk = (const float*)d_in[5];
  const float* bk = (const float*)d_in[6];
  const float* wv = (const float*)d_in[7];
  const float* bv = (const float*)d_in[8];
  // d_in[9] view_emb: row-constant score bias, cancelled by softmax -> unused
  const float* lng[3] = {(const float*)d_in[10], (const float*)d_in[12],
                         (const float*)d_in[14]};
  const float* lnb[3] = {(const float*)d_in[11], (const float*)d_in[13],
                         (const float*)d_in[15]};
  const float* bw = (const float*)d_in[16];
  const float* sw = (const float*)d_in[17];
  const float* scaler = (const float*)d_in[18];

  // workspace layout (bytes); basis aliases [qkvb|Pb|sc] (dead by then)
  char* w8 = (char*)d_ws;
  bf16* qkvb = (bf16*)(w8 + 0);              // [2*4096, 768] bf16  12.58 MB
  bf16* Pb = (bf16*)(w8 + 12582912);         // [2][4096,4096] bf16 67.11 MB
  float* sc = (float*)(w8 + 79691776);       // [4096,4096] f32     67.11 MB
  bf16* vT = (bf16*)(w8 + 146800640);        // [2][256,4096] bf16   4.19 MB
  float* att = (float*)(w8 + 150994944);     // [2*4096, 256] f32    8.39 MB
  bf16* tokb = (bf16*)(w8 + 159383552);      // [2*4096, 256] bf16   4.19 MB
  float* x = (float*)(w8 + 163577856);       // [2*4096, 768] f32   25.17 MB
  bf16* Wmat = (bf16*)(w8 + 188743680);      // [256, 6912] bf16     3.54 MB
  bf16* wqkvb = (bf16*)(w8 + 192282624);     // [768, 256] bf16      0.39 MB
  float* bqkv = (float*)(w8 + 192675840);    // [768] f32
  bf16* basis = (bf16*)(w8 + 0);             // [2*4096, 6912] bf16 113.2 MB

  prep_w<<<256, 256, 0, stream>>>(bw, sw, scaler, Wmat);
  prep_qkvw<<<768, 256, 0, stream>>>(wq, wk, wv, bq, bk, bv, wqkvb, bqkv);

  for (int v = 0; v < 3; ++v) {
    cast_tok<<<2048, 256, 0, stream>>>((const float4*)tok[v], tokb);
    // QKV: [8192,256] @ [768,256]^T -> qkvb [8192,768] bf16 (+bias)
    mfma_gemm_bt<bf16><<<dim3(6, 64, 1), 256, 0, stream>>>(
        tokb, wqkvb, bqkv, qkvb, 256, 256, 256, 768, 0, 0, 0, 1.0f);
    transpose_v<<<dim3(64, 4, 2), 256, 0, stream>>>(qkvb, vT);
    for (int b = 0; b < 2; ++b) {
      // scores: q @ k^T * 1/16 -> sc fp32
      mfma_gemm_bt<float><<<dim3(32, 32, 1), 256, 0, stream>>>(
          qkvb + (size_t)b * S * 768, qkvb + (size_t)b * S * 768 + 256,
          nullptr, sc, 256, 768, 768, 4096, 0, 0, 0, 0.0625f);
      softmax_kernel<<<4096, 256, 0, stream>>>(sc, Pb + (size_t)b * S * S);
    }
    // PV (both batches): P @ vT^T -> att fp32
    mfma_gemm_bt<float><<<dim3(2, 32, 2), 256, 0, stream>>>(
        Pb, vT, nullptr, att, 4096, 4096, 4096, 256, (size_t)S * S,
        (size_t)D * S, (size_t)S * D, 1.0f);
    resid_ln_kernel<<<8192, 256, 0, stream>>>(att, tok[v], lng[v], lnb[v], x, v);
  }

  basis_kernel<<<dim3(3, 8192, 1), 256, 0, stream>>>(x, basis);
  // KAN: basis @ Wmat^T -> out fp32
  mfma_gemm_bt<float><<<dim3(2, 64, 1), 256, 0, stream>>>(
      basis, Wmat, nullptr, (float*)d_out, 6912, 6912, 6912, 256, 0, 0, 0,
      1.0f);
}

// Round 5
// 606.284 us; speedup vs baseline: 5.7053x; 1.4434x over previous
//
#include <hip/hip_runtime.h>
#include <hip/hip_bf16.h>
#include <math.h>

// ---------------------------------------------------------------------------
// B=2, S=4096, D=256, IN=768, N_BASIS=8, spline grid h=0.4
// view_emb adds a row-constant to pre-softmax scores -> cancelled -> unused.
// R2-proven attention numerics (no flash). Softmax without max-subtraction:
// |q.k|/16 <= ~1.7 (Cauchy-Schwarz) so exp never overflows; scores GEMM
// epilogue writes unnormalized bf16 P = exp(acc/16); rowsum -> l; resid_ln
// divides by l. Mathematically identical to reference softmax.
// ---------------------------------------------------------------------------

typedef __hip_bfloat16 bf16;
using bf16x8 = __attribute__((ext_vector_type(8))) __bf16;
using f32x4  = __attribute__((ext_vector_type(4))) float;

__device__ __forceinline__ void load_lds16(const void* g, void* l) {
  __builtin_amdgcn_global_load_lds((__attribute__((address_space(1))) void*)g,
                                   (__attribute__((address_space(3))) void*)l,
                                   16, 0, 0);
}

__device__ __forceinline__ float wave_sum(float v) {
#pragma unroll
  for (int o = 32; o > 0; o >>= 1) v += __shfl_down(v, o, 64);
  return v;
}

// ---------------------------------------------------------------------------
// bf16 MFMA GEMM, BT form: C[m,n] = f(scale * sum_k A[m,k]*B[n,k] + bias[n])
// f = exp if EXP. 128x128 block, BK=32, 4 waves 2x2, 4x4 frags of 16x16x32.
// z decomposed as (hi=z>>1, lo=z&1) with separate strides (supports split-K
// and batch simultaneously).
// ---------------------------------------------------------------------------
template <typename OutT, bool EXP>
__global__ __launch_bounds__(256) void mfma_gemm_bt(
    const bf16* __restrict__ A, const bf16* __restrict__ B,
    const float* __restrict__ bias, OutT* __restrict__ C, int K, int lda,
    int ldb, int ldc, size_t zAh, size_t zAl, size_t zBh, size_t zBl,
    size_t zC, float scale) {
  __shared__ __align__(16) bf16 As[4096];
  __shared__ __align__(16) bf16 Bs[4096];
  const int tid = (int)threadIdx.x;
  const int lane = tid & 63;
  const int w = tid >> 6;
  const int m0 = (int)blockIdx.y << 7;
  const int n0 = (int)blockIdx.x << 7;
  const size_t z = blockIdx.z;
  A += (z >> 1) * zAh + (z & 1) * zAl;
  B += (z >> 1) * zBh + (z & 1) * zBl;
  C += z * zC;

  const int srow = lane >> 2;
  const int qg = (lane & 3) ^ ((lane >> 3) & 3);
  const int ci0 = w, ci1 = w + 4;
  const bf16* gA0 = A + (size_t)(m0 + ci0 * 16 + srow) * lda + qg * 8;
  const bf16* gA1 = A + (size_t)(m0 + ci1 * 16 + srow) * lda + qg * 8;
  const bf16* gB0 = B + (size_t)(n0 + ci0 * 16 + srow) * ldb + qg * 8;
  const bf16* gB1 = B + (size_t)(n0 + ci1 * 16 + srow) * ldb + qg * 8;
  bf16* lA0 = As + ci0 * 512;
  bf16* lA1 = As + ci1 * 512;
  bf16* lB0 = Bs + ci0 * 512;
  bf16* lB1 = Bs + ci1 * 512;

  const int m15 = lane & 15, quad = lane >> 4;
  const int fq = quad ^ ((m15 >> 1) & 3);
  const int aoff = m15 * 32 + fq * 8;
  const bf16* pA = As + ((w >> 1) << 11) + aoff;
  const bf16* pB = Bs + ((w & 1) << 11) + aoff;

  f32x4 acc[4][4];
#pragma unroll
  for (int mi = 0; mi < 4; ++mi)
#pragma unroll
    for (int ni = 0; ni < 4; ++ni) acc[mi][ni] = (f32x4)(0.0f);

  for (int k0 = 0; k0 < K; k0 += 32) {
    load_lds16(gA0, lA0);
    load_lds16(gA1, lA1);
    load_lds16(gB0, lB0);
    load_lds16(gB1, lB1);
    gA0 += 32; gA1 += 32; gB0 += 32; gB1 += 32;
    __syncthreads();
    bf16x8 av[4], bv[4];
#pragma unroll
    for (int i = 0; i < 4; ++i) {
      av[i] = *(const bf16x8*)(pA + i * 512);
      bv[i] = *(const bf16x8*)(pB + i * 512);
    }
#pragma unroll
    for (int mi = 0; mi < 4; ++mi)
#pragma unroll
      for (int ni = 0; ni < 4; ++ni)
        acc[mi][ni] = __builtin_amdgcn_mfma_f32_16x16x32_bf16(
            av[mi], bv[ni], acc[mi][ni], 0, 0, 0);
    __syncthreads();
  }

  const int crow = m0 + ((w >> 1) << 6) + quad * 4;
  const int ccol = n0 + ((w & 1) << 6) + m15;
#pragma unroll
  for (int ni = 0; ni < 4; ++ni) {
    const int col = ccol + ni * 16;
    const float bb = bias ? bias[col] : 0.0f;
#pragma unroll
    for (int mi = 0; mi < 4; ++mi) {
#pragma unroll
      for (int i = 0; i < 4; ++i) {
        const int row = crow + mi * 16 + i;
        float v = acc[mi][ni][i] * scale + bb;
        if constexpr (EXP) v = __expf(v);
        if constexpr (sizeof(OutT) == 2)
          C[(size_t)row * ldc + col] = __float2bfloat16(v);
        else
          C[(size_t)row * ldc + col] = v;
      }
    }
  }
}

// ---------------------------------------------------------------------------
// row sums of unnormalized bf16 P: l[row] = sum_col P[row][col], 4096 cols
// ---------------------------------------------------------------------------
__global__ __launch_bounds__(256) void rowsum_kernel(
    const bf16* __restrict__ P, float* __restrict__ l) {
  __shared__ float red[4];
  const int tid = (int)threadIdx.x;
  const bf16* p = P + (size_t)blockIdx.x * 4096 + tid * 16;
  float s = 0.f;
#pragma unroll
  for (int t = 0; t < 16; ++t) s += __bfloat162float(p[t]);
  s = wave_sum(s);
  if ((tid & 63) == 0) red[tid >> 6] = s;
  __syncthreads();
  if (tid == 0) l[blockIdx.x] = red[0] + red[1] + red[2] + red[3];
}

// ---------------------------------------------------------------------------
// residual + LayerNorm from split-K PV partials:
// att = (attp[b*2] + attp[b*2+1]) / l ;  x[n, vIdx*256+d] = LN(att+tok)
// ---------------------------------------------------------------------------
__global__ __launch_bounds__(256) void resid_ln_kernel(
    const float* __restrict__ attp, const float* __restrict__ l,
    const float* __restrict__ tok, const float* __restrict__ gamma,
    const float* __restrict__ beta, float* __restrict__ x, int vIdx) {
  __shared__ float red[4];
  const int n = (int)blockIdx.x;  // 0..8191 ; b = n>>12
  const int d = (int)threadIdx.x;
  const int b = n >> 12, r = n & 4095;
  const size_t base = ((size_t)(b * 2) * 4096 + r) * 256 + d;
  const float a0 = attp[base];
  const float a1 = attp[base + (size_t)4096 * 256];
  const float invl = 1.0f / l[b * 4096 + r];
  const float y = (a0 + a1) * invl + tok[(size_t)n * 256 + d];
  float s = wave_sum(y);
  if ((d & 63) == 0) red[d >> 6] = s;
  __syncthreads();
  const float mu = (red[0] + red[1] + red[2] + red[3]) * (1.0f / 256.0f);
  __syncthreads();
  const float c = y - mu;
  float s2 = wave_sum(c * c);
  if ((d & 63) == 0) red[d >> 6] = s2;
  __syncthreads();
  const float var = (red[0] + red[1] + red[2] + red[3]) * (1.0f / 256.0f);
  const float rs = rsqrtf(var + 1e-5f);
  x[(size_t)n * 768 + vIdx * 256 + d] = c * rs * gamma[d] + beta[d];
}

// ---------------------------------------------------------------------------
// Wmat[o][i*10+f]: f<8 -> sw[o,i,f]*scaler[o,i]; f=8,9 -> bw[o,i] (hi+lo chans)
// ---------------------------------------------------------------------------
__global__ __launch_bounds__(256) void prep_w(
    const float* __restrict__ bw, const float* __restrict__ sw,
    const float* __restrict__ scaler, bf16* __restrict__ Wmat) {
  const int o = blockIdx.x;
  for (int ii = 0; ii < 3; ++ii) {
    const int i = ii * 256 + (int)threadIdx.x;
    const float s = scaler[(size_t)o * 768 + i];
    bf16* p = Wmat + (size_t)o * 7680 + i * 10;
    const float* swp = sw + ((size_t)o * 768 + i) * 8;
#pragma unroll
    for (int f = 0; f < 8; ++f) p[f] = __float2bfloat16(swp[f] * s);
    const bf16 bwb = __float2bfloat16(bw[(size_t)o * 768 + i]);
    p[8] = bwb;
    p[9] = bwb;
  }
}

__global__ __launch_bounds__(256) void prep_qkvw(
    const float* __restrict__ wq, const float* __restrict__ wk,
    const float* __restrict__ wv, const float* __restrict__ bq,
    const float* __restrict__ bk, const float* __restrict__ bv,
    bf16* __restrict__ wqkvb, float* __restrict__ bqkv) {
  const int idx = blockIdx.x * 256 + (int)threadIdx.x;
  const int row = idx >> 8, col = idx & 255;
  const float* src = row < 256 ? wq : (row < 512 ? wk : wv);
  wqkvb[idx] = __float2bfloat16(src[((row & 255) << 8) + col]);
  if (idx < 768)
    bqkv[idx] = idx < 256 ? bq[idx] : (idx < 512 ? bk[idx - 256] : bv[idx - 512]);
}

__global__ __launch_bounds__(256) void cast_tok3(
    const float4* __restrict__ t0, const float4* __restrict__ t1,
    const float4* __restrict__ t2, bf16* __restrict__ dst) {
  const int vv = blockIdx.y;
  const float4* src = vv == 0 ? t0 : (vv == 1 ? t1 : t2);
  const int idx = blockIdx.x * 256 + (int)threadIdx.x;
  const float4 val = src[idx];
  bf16* p = dst + (size_t)vv * 2097152 + (size_t)idx * 4;
  p[0] = __float2bfloat16(val.x);
  p[1] = __float2bfloat16(val.y);
  p[2] = __float2bfloat16(val.z);
  p[3] = __float2bfloat16(val.w);
}

// vT[z][d][s] = qkv[z*4096+s][512+d]
__global__ __launch_bounds__(256) void transpose_v(
    const bf16* __restrict__ qkv, bf16* __restrict__ vT) {
  __shared__ bf16 tle[64][65];
  const int s0 = blockIdx.x << 6, d0 = blockIdx.y << 6, z = blockIdx.z;
  const int tid = (int)threadIdx.x;
  const int c = tid & 63, rr = tid >> 6;
  for (int r = 0; r < 64; r += 4)
    tle[r + rr][c] = qkv[(size_t)(z * 4096 + s0 + r + rr) * 768 + 512 + d0 + c];
  __syncthreads();
  for (int r = 0; r < 64; r += 4)
    vT[(size_t)z * 1048576 + (size_t)(d0 + r + rr) * 4096 + s0 + c] =
        tle[c][r + rr];
}

// ---------------------------------------------------------------------------
// basis[n][i*10+f]: f<8 cubic B-splines of x[n,i]; f=8 silu hi; f=9 silu lo
// ---------------------------------------------------------------------------
__global__ __launch_bounds__(256) void basis_kernel(
    const float* __restrict__ x, bf16* __restrict__ basis) {
  const int i = blockIdx.x * 256 + (int)threadIdx.x;  // 0..767
  const int n = blockIdx.y;
  const float xv = x[(size_t)n * 768 + i];
  float b[11];
#pragma unroll
  for (int m = 0; m < 11; ++m) {
    const float g0 = 0.4f * (float)(m - 3) - 1.0f;
    const float g1 = 0.4f * (float)(m - 2) - 1.0f;
    b[m] = (xv >= g0 && xv < g1) ? 1.0f : 0.0f;
  }
#pragma unroll
  for (int k = 1; k <= 3; ++k) {
    const float inv = 1.0f / (0.4f * (float)k);
#pragma unroll
    for (int m = 0; m + k < 11; ++m) {
      const float gm = 0.4f * (float)(m - 3) - 1.0f;
      const float gmk1 = 0.4f * (float)(m + k - 2) - 1.0f;
      b[m] = (xv - gm) * inv * b[m] + (gmk1 - xv) * inv * b[m + 1];
    }
  }
  bf16* p = basis + (size_t)n * 7680 + i * 10;
#pragma unroll
  for (int f = 0; f < 8; ++f) p[f] = __float2bfloat16(b[f]);
  const float sil = xv / (1.0f + __expf(-xv));
  const bf16 hi = __float2bfloat16(sil);
  p[8] = hi;
  p[9] = __float2bfloat16(sil - __bfloat162float(hi));
}

__global__ __launch_bounds__(256) void combine_kernel(
    const float4* __restrict__ p0, const float4* __restrict__ p1,
    float4* __restrict__ out) {
  const int idx = blockIdx.x * 256 + (int)threadIdx.x;
  const float4 a = p0[idx], b = p1[idx];
  out[idx] = make_float4(a.x + b.x, a.y + b.y, a.z + b.z, a.w + b.w);
}

// ---------------------------------------------------------------------------
extern "C" void kernel_launch(void* const* d_in, const int* in_sizes, int n_in,
                              void* d_out, int out_size, void* d_ws,
                              size_t ws_size, hipStream_t stream) {
  const float* tok[3] = {(const float*)d_in[0], (const float*)d_in[1],
                         (const float*)d_in[2]};
  const float* wq = (const float*)d_in[3];
  const float* bq = (const float*)d_in[4];
  const float* wk = (const float*)d_in[5];
  const float* bk = (const float*)d_in[6];
  const float* wv = (const float*)d_in[7];
  const float* bv = (const float*)d_in[8];
  // d_in[9] view_emb unused (softmax-invariant)
  const float* lng[3] = {(const float*)d_in[10], (const float*)d_in[12],
                         (const float*)d_in[14]};
  const float* lnb[3] = {(const float*)d_in[11], (const float*)d_in[13],
                         (const float*)d_in[15]};
  const float* bw = (const float*)d_in[16];
  const float* sw = (const float*)d_in[17];
  const float* scaler = (const float*)d_in[18];

  // workspace layout (bytes). basis [0,125.83MB) aliases tokb+qkv+vT+Pb,
  // all dead before basis_kernel runs. Total ~193.1 MB.
  char* w8 = (char*)d_ws;
  bf16* tokb = (bf16*)(w8 + 0);              // [3*8192,256]   12.58 MB
  bf16* qkv = (bf16*)(w8 + 12582912);        // [3*8192,768]   37.75 MB
  bf16* vT = (bf16*)(w8 + 50331648);         // [6][256][4096] 12.58 MB
  bf16* Pb = (bf16*)(w8 + 62914560);         // [2][4096,4096] 67.11 MB
  float* lrow = (float*)(w8 + 130023424);    // [2][4096]       0.03 MB
  float* attp = (float*)(w8 + 130056192);    // [4][4096,256]  16.78 MB
  float* x = (float*)(w8 + 146833408);       // [8192,768]     25.17 MB
  bf16* Wmat = (bf16*)(w8 + 171999232);      // [256,7680]      3.93 MB
  bf16* wqkvb = (bf16*)(w8 + 175931392);     // [768,256]       0.39 MB
  float* bqkv = (float*)(w8 + 176324608);    // [768]
  float* pout = (float*)(w8 + 176327680);    // [2][8192,256]  16.78 MB
  bf16* basis = (bf16*)(w8 + 0);             // [8192,7680]   125.83 MB alias

  prep_w<<<256, 256, 0, stream>>>(bw, sw, scaler, Wmat);
  prep_qkvw<<<768, 256, 0, stream>>>(wq, wk, wv, bq, bk, bv, wqkvb, bqkv);
  cast_tok3<<<dim3(2048, 3), 256, 0, stream>>>(
      (const float4*)tok[0], (const float4*)tok[1], (const float4*)tok[2],
      tokb);

  // QKV all views: [24576,256] @ [768,256]^T + bias -> qkv bf16
  mfma_gemm_bt<bf16, false><<<dim3(6, 192, 1), 256, 0, stream>>>(
      tokb, wqkvb, bqkv, qkv, 256, 256, 256, 768, 0, 0, 0, 0, 0, 1.0f);
  transpose_v<<<dim3(64, 4, 6), 256, 0, stream>>>(qkv, vT);

  for (int v = 0; v < 3; ++v) {
    for (int b = 0; b < 2; ++b) {
      const bf16* qb = qkv + (size_t)(2 * v + b) * 4096 * 768;
      // P = exp(q@k^T / 16), unnormalized bf16
      mfma_gemm_bt<bf16, true><<<dim3(32, 32, 1), 256, 0, stream>>>(
          qb, qb + 256, nullptr, Pb + (size_t)b * 16777216, 256, 768, 768,
          4096, 0, 0, 0, 0, 0, 0.0625f);
      rowsum_kernel<<<4096, 256, 0, stream>>>(Pb + (size_t)b * 16777216,
                                              lrow + b * 4096);
    }
    // PV split-K: z=(b,kh): attp[z] = P[b][:,kh*2048:] @ V^T[b][:,kh*2048:]^T
    mfma_gemm_bt<float, false><<<dim3(2, 32, 4), 256, 0, stream>>>(
        Pb, vT + (size_t)(2 * v) * 1048576, nullptr, attp, 2048, 4096, 4096,
        256, 16777216, 2048, 1048576, 2048, 1048576, 1.0f);
    resid_ln_kernel<<<8192, 256, 0, stream>>>(attp, lrow, tok[v], lng[v],
                                              lnb[v], x, v);
  }

  basis_kernel<<<dim3(3, 8192), 256, 0, stream>>>(x, basis);
  // KAN split-K: z=kh: pout[z] = basis[:,kh*3840:] @ Wmat[:,kh*3840:]^T
  mfma_gemm_bt<float, false><<<dim3(2, 64, 2), 256, 0, stream>>>(
      basis, Wmat, nullptr, pout, 3840, 7680, 7680, 256, 0, 3840, 0, 3840,
      2097152, 1.0f);
  combine_kernel<<<2048, 256, 0, stream>>>(
      (const float4*)pout, (const float4*)(pout + (size_t)8192 * 256),
      (float4*)d_out);
}

// Round 6
// 544.656 us; speedup vs baseline: 6.3508x; 1.1132x over previous
//
#include <hip/hip_runtime.h>
#include <hip/hip_bf16.h>
#include <math.h>

// ---------------------------------------------------------------------------
// B=2, S=4096, D=256, IN=768, N_BASIS=8, spline grid h=0.4
// view_emb adds a row-constant to pre-softmax scores -> cancelled -> unused.
// R2-proven attention numerics. Softmax without max-subtraction:
// |q.k|/16 <= ~1.7 (Cauchy-Schwarz) -> exp in [0.2,5.5], no overflow.
// Scores GEMM epilogue writes unnormalized bf16 P = exp(acc/16) AND
// deterministic per-row partial sums (lpart, 64 col-half partials/row).
// resid_ln reduces lpart -> l and normalizes. Split-K=4 on PV and KAN for
// 2 blocks/CU occupancy (R5 counters: 1 block/CU was the limiter).
// ---------------------------------------------------------------------------

typedef __hip_bfloat16 bf16;
using bf16x8 = __attribute__((ext_vector_type(8))) __bf16;
using f32x4  = __attribute__((ext_vector_type(4))) float;

__device__ __forceinline__ void load_lds16(const void* g, void* l) {
  __builtin_amdgcn_global_load_lds((__attribute__((address_space(1))) void*)g,
                                   (__attribute__((address_space(3))) void*)l,
                                   16, 0, 0);
}

__device__ __forceinline__ float wave_sum(float v) {
#pragma unroll
  for (int o = 32; o > 0; o >>= 1) v += __shfl_down(v, o, 64);
  return v;
}

// ---------------------------------------------------------------------------
// bf16 MFMA GEMM, BT form: C[m,n] = f(scale * sum_k A[m,k]*B[n,k] + bias[n])
// f = exp if EXP (also emits lpart row partials). 128x128 block, BK=32,
// 4 waves 2x2, 4x4 frags of 16x16x32. z decomposed (hi=z>>zshift,
// lo=z&mask) with separate A/B strides -> supports batch x split-K.
// ---------------------------------------------------------------------------
template <typename OutT, bool EXP>
__global__ __launch_bounds__(256) void mfma_gemm_bt(
    const bf16* __restrict__ A, const bf16* __restrict__ B,
    const float* __restrict__ bias, OutT* __restrict__ C,
    float* __restrict__ lpart, int K, int lda, int ldb, int ldc, int zshift,
    size_t zAh, size_t zAl, size_t zBh, size_t zBl, size_t zC, float scale) {
  __shared__ __align__(16) bf16 As[4096];
  __shared__ __align__(16) bf16 Bs[4096];
  const int tid = (int)threadIdx.x;
  const int lane = tid & 63;
  const int w = tid >> 6;
  const int m0 = (int)blockIdx.y << 7;
  const int n0 = (int)blockIdx.x << 7;
  const size_t z = blockIdx.z;
  const size_t zlo = z & (((size_t)1 << zshift) - 1);
  A += (z >> zshift) * zAh + zlo * zAl;
  B += (z >> zshift) * zBh + zlo * zBl;
  C += z * zC;

  const int srow = lane >> 2;
  const int qg = (lane & 3) ^ ((lane >> 3) & 3);
  const int ci0 = w, ci1 = w + 4;
  const bf16* gA0 = A + (size_t)(m0 + ci0 * 16 + srow) * lda + qg * 8;
  const bf16* gA1 = A + (size_t)(m0 + ci1 * 16 + srow) * lda + qg * 8;
  const bf16* gB0 = B + (size_t)(n0 + ci0 * 16 + srow) * ldb + qg * 8;
  const bf16* gB1 = B + (size_t)(n0 + ci1 * 16 + srow) * ldb + qg * 8;
  bf16* lA0 = As + ci0 * 512;
  bf16* lA1 = As + ci1 * 512;
  bf16* lB0 = Bs + ci0 * 512;
  bf16* lB1 = Bs + ci1 * 512;

  const int m15 = lane & 15, quad = lane >> 4;
  const int fq = quad ^ ((m15 >> 1) & 3);
  const int aoff = m15 * 32 + fq * 8;
  const bf16* pA = As + ((w >> 1) << 11) + aoff;
  const bf16* pB = Bs + ((w & 1) << 11) + aoff;

  f32x4 acc[4][4];
#pragma unroll
  for (int mi = 0; mi < 4; ++mi)
#pragma unroll
    for (int ni = 0; ni < 4; ++ni) acc[mi][ni] = (f32x4)(0.0f);

  for (int k0 = 0; k0 < K; k0 += 32) {
    load_lds16(gA0, lA0);
    load_lds16(gA1, lA1);
    load_lds16(gB0, lB0);
    load_lds16(gB1, lB1);
    gA0 += 32; gA1 += 32; gB0 += 32; gB1 += 32;
    __syncthreads();
    bf16x8 av[4], bv[4];
#pragma unroll
    for (int i = 0; i < 4; ++i) {
      av[i] = *(const bf16x8*)(pA + i * 512);
      bv[i] = *(const bf16x8*)(pB + i * 512);
    }
#pragma unroll
    for (int mi = 0; mi < 4; ++mi)
#pragma unroll
      for (int ni = 0; ni < 4; ++ni)
        acc[mi][ni] = __builtin_amdgcn_mfma_f32_16x16x32_bf16(
            av[mi], bv[ni], acc[mi][ni], 0, 0, 0);
    __syncthreads();
  }

  const int crow = m0 + ((w >> 1) << 6) + quad * 4;
  const int ccol = n0 + ((w & 1) << 6) + m15;
  float rs[4][4] = {};
#pragma unroll
  for (int ni = 0; ni < 4; ++ni) {
    const int col = ccol + ni * 16;
    const float bb = bias ? bias[col] : 0.0f;
#pragma unroll
    for (int mi = 0; mi < 4; ++mi) {
#pragma unroll
      for (int i = 0; i < 4; ++i) {
        const int row = crow + mi * 16 + i;
        float v = acc[mi][ni][i] * scale + bb;
        if constexpr (EXP) {
          v = __expf(v);
          rs[mi][i] += v;
        }
        if constexpr (sizeof(OutT) == 2)
          C[(size_t)row * ldc + col] = __float2bfloat16(v);
        else
          C[(size_t)row * ldc + col] = v;
      }
    }
  }
  if constexpr (EXP) {
    // per-row partial sums over this block's col-half (deterministic, no
    // atomics): col-half index ch in [0,64), one writer lane per row.
    const int ch = ((int)blockIdx.x << 1) | (w & 1);
#pragma unroll
    for (int mi = 0; mi < 4; ++mi)
#pragma unroll
      for (int i = 0; i < 4; ++i) {
        float sv = rs[mi][i];
        sv += __shfl_xor(sv, 1);
        sv += __shfl_xor(sv, 2);
        sv += __shfl_xor(sv, 4);
        sv += __shfl_xor(sv, 8);
        if (m15 == 0)
          lpart[(size_t)ch * 4096 + crow + mi * 16 + i] = sv;
      }
  }
}

// ---------------------------------------------------------------------------
// residual + LayerNorm from split-K PV partials and lpart row sums:
// l = sum_ch lpart[b][ch][r]; att = (sum_kh attp[b*4+kh]) / l
// x[n, vIdx*256+d] = LN(att + tok)
// ---------------------------------------------------------------------------
__global__ __launch_bounds__(256) void resid_ln_kernel(
    const float* __restrict__ attp, const float* __restrict__ lpart,
    const float* __restrict__ tok, const float* __restrict__ gamma,
    const float* __restrict__ beta, float* __restrict__ x, int vIdx) {
  __shared__ float red[4];
  __shared__ float sinvl;
  const int n = (int)blockIdx.x;  // 0..8191 ; b = n>>12
  const int d = (int)threadIdx.x;
  const int b = n >> 12, r = n & 4095;
  float ls = 0.f;
  if (d < 64) ls = lpart[((size_t)(b * 64 + d)) * 4096 + r];
  ls = wave_sum(ls);
  if (d == 0) sinvl = 1.0f / ls;
  const size_t abase = (size_t)(b * 4) * 1048576 + (size_t)r * 256 + d;
  const float asum = attp[abase] + attp[abase + 1048576] +
                     attp[abase + 2097152] + attp[abase + 3145728];
  __syncthreads();
  const float y = asum * sinvl + tok[(size_t)n * 256 + d];
  float s = wave_sum(y);
  if ((d & 63) == 0) red[d >> 6] = s;
  __syncthreads();
  const float mu = (red[0] + red[1] + red[2] + red[3]) * (1.0f / 256.0f);
  __syncthreads();
  const float c = y - mu;
  float s2 = wave_sum(c * c);
  if ((d & 63) == 0) red[d >> 6] = s2;
  __syncthreads();
  const float var = (red[0] + red[1] + red[2] + red[3]) * (1.0f / 256.0f);
  const float rstd = rsqrtf(var + 1e-5f);
  x[(size_t)n * 768 + vIdx * 256 + d] = c * rstd * gamma[d] + beta[d];
}

// ---------------------------------------------------------------------------
// Wmat[o][i*9+f]: f<8 -> sw[o,i,f]*scaler[o,i]; f=8 -> bw[o,i]
// ---------------------------------------------------------------------------
__global__ __launch_bounds__(256) void prep_w(
    const float* __restrict__ bw, const float* __restrict__ sw,
    const float* __restrict__ scaler, bf16* __restrict__ Wmat) {
  const int o = blockIdx.x;
  for (int ii = 0; ii < 3; ++ii) {
    const int i = ii * 256 + (int)threadIdx.x;
    const float s = scaler[(size_t)o * 768 + i];
    bf16* p = Wmat + (size_t)o * 6912 + i * 9;
    const float* swp = sw + ((size_t)o * 768 + i) * 8;
#pragma unroll
    for (int f = 0; f < 8; ++f) p[f] = __float2bfloat16(swp[f] * s);
    p[8] = __float2bfloat16(bw[(size_t)o * 768 + i]);
  }
}

__global__ __launch_bounds__(256) void prep_qkvw(
    const float* __restrict__ wq, const float* __restrict__ wk,
    const float* __restrict__ wv, const float* __restrict__ bq,
    const float* __restrict__ bk, const float* __restrict__ bv,
    bf16* __restrict__ wqkvb, float* __restrict__ bqkv) {
  const int idx = blockIdx.x * 256 + (int)threadIdx.x;
  const int row = idx >> 8, col = idx & 255;
  const float* src = row < 256 ? wq : (row < 512 ? wk : wv);
  wqkvb[idx] = __float2bfloat16(src[((row & 255) << 8) + col]);
  if (idx < 768)
    bqkv[idx] = idx < 256 ? bq[idx] : (idx < 512 ? bk[idx - 256] : bv[idx - 512]);
}

__global__ __launch_bounds__(256) void cast_tok3(
    const float4* __restrict__ t0, const float4* __restrict__ t1,
    const float4* __restrict__ t2, bf16* __restrict__ dst) {
  const int vv = blockIdx.y;
  const float4* src = vv == 0 ? t0 : (vv == 1 ? t1 : t2);
  const int idx = blockIdx.x * 256 + (int)threadIdx.x;
  const float4 val = src[idx];
  bf16* p = dst + (size_t)vv * 2097152 + (size_t)idx * 4;
  p[0] = __float2bfloat16(val.x);
  p[1] = __float2bfloat16(val.y);
  p[2] = __float2bfloat16(val.z);
  p[3] = __float2bfloat16(val.w);
}

// vT[z][d][s] = qkv[z*4096+s][512+d]
__global__ __launch_bounds__(256) void transpose_v(
    const bf16* __restrict__ qkv, bf16* __restrict__ vT) {
  __shared__ bf16 tle[64][65];
  const int s0 = blockIdx.x << 6, d0 = blockIdx.y << 6, z = blockIdx.z;
  const int tid = (int)threadIdx.x;
  const int c = tid & 63, rr = tid >> 6;
  for (int r = 0; r < 64; r += 4)
    tle[r + rr][c] = qkv[(size_t)(z * 4096 + s0 + r + rr) * 768 + 512 + d0 + c];
  __syncthreads();
  for (int r = 0; r < 64; r += 4)
    vT[(size_t)z * 1048576 + (size_t)(d0 + r + rr) * 4096 + s0 + c] =
        tle[c][r + rr];
}

// ---------------------------------------------------------------------------
// basis[n][i*9+f]: f<8 cubic B-splines of x[n,i]; f=8 silu(x)
// ---------------------------------------------------------------------------
__global__ __launch_bounds__(256) void basis_kernel(
    const float* __restrict__ x, bf16* __restrict__ basis) {
  const int i = blockIdx.x * 256 + (int)threadIdx.x;  // 0..767
  const int n = blockIdx.y;
  const float xv = x[(size_t)n * 768 + i];
  float b[11];
#pragma unroll
  for (int m = 0; m < 11; ++m) {
    const float g0 = 0.4f * (float)(m - 3) - 1.0f;
    const float g1 = 0.4f * (float)(m - 2) - 1.0f;
    b[m] = (xv >= g0 && xv < g1) ? 1.0f : 0.0f;
  }
#pragma unroll
  for (int k = 1; k <= 3; ++k) {
    const float inv = 1.0f / (0.4f * (float)k);
#pragma unroll
    for (int m = 0; m + k < 11; ++m) {
      const float gm = 0.4f * (float)(m - 3) - 1.0f;
      const float gmk1 = 0.4f * (float)(m + k - 2) - 1.0f;
      b[m] = (xv - gm) * inv * b[m] + (gmk1 - xv) * inv * b[m + 1];
    }
  }
  bf16* p = basis + (size_t)n * 6912 + i * 9;
#pragma unroll
  for (int f = 0; f < 8; ++f) p[f] = __float2bfloat16(b[f]);
  p[8] = __float2bfloat16(xv / (1.0f + __expf(-xv)));
}

__global__ __launch_bounds__(256) void combine4_kernel(
    const float4* __restrict__ p, float4* __restrict__ out) {
  const int idx = blockIdx.x * 256 + (int)threadIdx.x;
  const float4 a = p[idx];
  const float4 b = p[idx + 524288];
  const float4 c = p[idx + 1048576];
  const float4 d = p[idx + 1572864];
  out[idx] =
      make_float4(a.x + b.x + c.x + d.x, a.y + b.y + c.y + d.y,
                  a.z + b.z + c.z + d.z, a.w + b.w + c.w + d.w);
}

// ---------------------------------------------------------------------------
extern "C" void kernel_launch(void* const* d_in, const int* in_sizes, int n_in,
                              void* d_out, int out_size, void* d_ws,
                              size_t ws_size, hipStream_t stream) {
  const float* tok[3] = {(const float*)d_in[0], (const float*)d_in[1],
                         (const float*)d_in[2]};
  const float* wq = (const float*)d_in[3];
  const float* bq = (const float*)d_in[4];
  const float* wk = (const float*)d_in[5];
  const float* bk = (const float*)d_in[6];
  const float* wv = (const float*)d_in[7];
  const float* bv = (const float*)d_in[8];
  // d_in[9] view_emb unused (softmax-invariant)
  const float* lng[3] = {(const float*)d_in[10], (const float*)d_in[12],
                         (const float*)d_in[14]};
  const float* lnb[3] = {(const float*)d_in[11], (const float*)d_in[13],
                         (const float*)d_in[15]};
  const float* bw = (const float*)d_in[16];
  const float* sw = (const float*)d_in[17];
  const float* scaler = (const float*)d_in[18];

  // workspace layout (bytes), total ~194.8 MB.
  // basis [0,113.25M) aliases tokb+qkv+vT+Pb (all dead before basis).
  // pout aliases attp (dead after last resid_ln, before KAN GEMM).
  char* w8 = (char*)d_ws;
  bf16* tokb = (bf16*)(w8 + 0);              // [3*8192,256]    12.58 MB
  bf16* qkv = (bf16*)(w8 + 12582912);        // [3*8192,768]    37.75 MB
  bf16* vT = (bf16*)(w8 + 50331648);         // [6][256][4096]  12.58 MB
  bf16* Pb = (bf16*)(w8 + 62914560);         // [2][4096,4096]  67.11 MB
  float* lpart = (float*)(w8 + 130023424);   // [2][64][4096]    2.10 MB
  float* attp = (float*)(w8 + 132120576);    // [8][4096,256]   33.55 MB
  float* x = (float*)(w8 + 165675008);       // [8192,768]      25.17 MB
  bf16* Wmat = (bf16*)(w8 + 190840832);      // [256,6912]       3.54 MB
  bf16* wqkvb = (bf16*)(w8 + 194379776);     // [768,256]        0.39 MB
  float* bqkv = (float*)(w8 + 194772992);    // [768]
  bf16* basis = (bf16*)(w8 + 0);             // [8192,6912] alias
  float* pout = attp;                        // [4][8192,256] alias

  prep_w<<<256, 256, 0, stream>>>(bw, sw, scaler, Wmat);
  prep_qkvw<<<768, 256, 0, stream>>>(wq, wk, wv, bq, bk, bv, wqkvb, bqkv);
  cast_tok3<<<dim3(2048, 3), 256, 0, stream>>>(
      (const float4*)tok[0], (const float4*)tok[1], (const float4*)tok[2],
      tokb);

  // QKV all views: [24576,256] @ [768,256]^T + bias -> qkv bf16
  mfma_gemm_bt<bf16, false><<<dim3(6, 192, 1), 256, 0, stream>>>(
      tokb, wqkvb, bqkv, qkv, nullptr, 256, 256, 256, 768, 1, 0, 0, 0, 0, 0,
      1.0f);
  transpose_v<<<dim3(64, 4, 6), 256, 0, stream>>>(qkv, vT);

  for (int v = 0; v < 3; ++v) {
    for (int b = 0; b < 2; ++b) {
      const bf16* qb = qkv + (size_t)(2 * v + b) * 4096 * 768;
      // P = exp(q@k^T/16) bf16 + lpart row partials (fused)
      mfma_gemm_bt<bf16, true><<<dim3(32, 32, 1), 256, 0, stream>>>(
          qb, qb + 256, nullptr, Pb + (size_t)b * 16777216,
          lpart + (size_t)b * 262144, 256, 768, 768, 4096, 1, 0, 0, 0, 0, 0,
          0.0625f);
    }
    // PV split-K=4: z=(b,kh): attp[z] = P[b][:,kh*1024+:1024] @ V^T-part
    mfma_gemm_bt<float, false><<<dim3(2, 32, 8), 256, 0, stream>>>(
        Pb, vT + (size_t)(2 * v) * 1048576, nullptr, attp, nullptr, 1024,
        4096, 4096, 256, 2, 16777216, 1024, 1048576, 1024, 1048576, 1.0f);
    resid_ln_kernel<<<8192, 256, 0, stream>>>(attp, lpart, tok[v], lng[v],
                                              lnb[v], x, v);
  }

  basis_kernel<<<dim3(3, 8192), 256, 0, stream>>>(x, basis);
  // KAN split-K=4: z=kh: pout[z] = basis[:,kh*1728+:1728] @ Wmat-part
  mfma_gemm_bt<float, false><<<dim3(2, 64, 4), 256, 0, stream>>>(
      basis, Wmat, nullptr, pout, nullptr, 1728, 6912, 6912, 256, 2, 0, 1728,
      0, 1728, 2097152, 1.0f);
  combine4_kernel<<<2048, 256, 0, stream>>>((const float4*)pout,
                                            (float4*)d_out);
}